// Round 8
// baseline (130.854 us; speedup 1.0000x reference)
//
#include <hip/hip_runtime.h>
#include <math.h>

#define D 128
#define K 1024

typedef __attribute__((ext_vector_type(8))) short bf16x8;
typedef __attribute__((ext_vector_type(4))) float f32x4;
typedef unsigned short u16;

// ws layout:
// [0,4096)        hist (1024 int)
// [4096,4100)     loss accumulator
// [8192,12288)    cnorm (1024 f32)
// [16384,540672)  frag image (512 KB): code-major [1024][hi128|lo128] u16

__device__ __forceinline__ u16 f2bf(float x) {
    union { float f; unsigned u; } v; v.f = x;
    unsigned r = (v.u + 0x7FFFu + ((v.u >> 16) & 1u)) >> 16;
    return (u16)r;
}
__device__ __forceinline__ float bf2f(u16 b) {
    union { float f; unsigned u; } v; v.u = ((unsigned)b) << 16;
    return v.f;
}

__device__ __forceinline__ void t2merge(float& v1, int& i1, float& v2, int& i2,
                                        float bv1, int bi1, float bv2, int bi2) {
    if (bv1 < v1 || (bv1 == v1 && bi1 < i1)) {
        v2 = v1; i2 = i1;
        v1 = bv1; i1 = bi1;
        if (bv2 < v2 || (bv2 == v2 && bi2 < i2)) { v2 = bv2; i2 = bi2; }
    } else {
        if (bv1 < v2 || (bv1 == v2 && bi1 < i2)) { v2 = bv1; i2 = bi1; }
    }
}

// codebook -> code-major bf16 hi/lo fragment image + cnorm; also zeros hist/loss
// (replaces the hipMemsetAsync graph node, which profiled anomalously slow)
__global__ void prep2(const float* __restrict__ cb, u16* __restrict__ frag,
                      float* __restrict__ cnorm, int* __restrict__ hist,
                      float* __restrict__ loss_accum) {
    int tid = blockIdx.x * blockDim.x + threadIdx.x;   // 0..32767, one float4/thread
    if (tid < K) hist[tid] = 0;
    if (tid == K) loss_accum[0] = 0.f;
    int code = tid >> 5, d4 = tid & 31;
    float4 v = reinterpret_cast<const float4*>(cb)[tid];
    u16 h0 = f2bf(v.x), h1 = f2bf(v.y), h2 = f2bf(v.z), h3 = f2bf(v.w);
    u16 l0 = f2bf(v.x - bf2f(h0)), l1 = f2bf(v.y - bf2f(h1));
    u16 l2 = f2bf(v.z - bf2f(h2)), l3 = f2bf(v.w - bf2f(h3));
    u16* base = frag + (size_t)code * 256;
    *reinterpret_cast<ushort4*>(base + d4 * 4) = make_ushort4(h0, h1, h2, h3);
    *reinterpret_cast<ushort4*>(base + 128 + d4 * 4) = make_ushort4(l0, l1, l2, l3);
    float s = v.x * v.x + v.y * v.y + v.z * v.z + v.w * v.w;
#pragma unroll
    for (int m = 1; m <= 16; m <<= 1) s += __shfl_xor(s, m);
    if (d4 == 0) cnorm[code] = s;
}

// FUSED kernel: 512 blocks x 512 thr (8 waves). Block owns rows blk*64..+63 x ALL 1024 codes.
// cg in {0,1}: wave's 64-code register tile reloaded between halves (L2-resident frag).
// Top-2 partials -> LDS (no global part buffer, no merge kernel). Epilogue does
// fp64 refine + idx + hist + loss + zq in-kernel.
__global__ __launch_bounds__(512, 2)
void vq_all(const float* __restrict__ z, const float* __restrict__ codebook,
            const u16* __restrict__ frag, const float* __restrict__ cnorm,
            int* __restrict__ hist, float* __restrict__ loss_accum,
            float* __restrict__ out_zq, float* __restrict__ out_idx,
            float* __restrict__ out_dist) {
    __shared__ u16 zsh[16384];          // 32 KB: hi 16K | lo 16K, XOR-swizzled
    __shared__ float4 scr[16 * 64];     // 16 KB top-2 scratch, slot-major [16][64]
    __shared__ float cn_s[K];
    __shared__ float xn_s[64];
    __shared__ int bi_s[64], si_s[64], best_s[64];

    const int t = threadIdx.x;
    const int lane = t & 63;
    const int wave = t >> 6;            // 0..7
    const int lr = lane & 15, lg = lane >> 4;
    const int row_base = blockIdx.x * 64;

    if (t < 64) xn_s[t] = 0.f;
    cn_s[t] = cnorm[t];
    cn_s[t + 512] = cnorm[t + 512];
    __syncthreads();

    // ---- stage + convert z tile (64 rows x 128) hi/lo, XOR-swizzled ----
    {
        const float4* zg = reinterpret_cast<const float4*>(z + (size_t)row_base * D);
#pragma unroll
        for (int k = 0; k < 4; ++k) {
            int f = t + k * 512;            // 0..2047
            int r = f >> 5, d4 = f & 31;
            float4 v = zg[f];
            u16 h0 = f2bf(v.x), h1 = f2bf(v.y), h2 = f2bf(v.z), h3 = f2bf(v.w);
            u16 l0 = f2bf(v.x - bf2f(h0)), l1 = f2bf(v.y - bf2f(h1));
            u16 l2 = f2bf(v.z - bf2f(h2)), l3 = f2bf(v.w - bf2f(h3));
            int sb = (r * 256 + d4 * 8) ^ ((r & 7) << 4);
            *reinterpret_cast<ushort4*>((char*)zsh + sb) = make_ushort4(h0, h1, h2, h3);
            *reinterpret_cast<ushort4*>((char*)zsh + 16384 + sb) = make_ushort4(l0, l1, l2, l3);
            atomicAdd(&xn_s[r], v.x * v.x + v.y * v.y + v.z * v.z + v.w * v.w);
        }
    }
    __syncthreads();    // z tile + xn ready

#pragma unroll 1
    for (int cg = 0; cg < 2; ++cg) {
        // ---- (re)load this wave's 64 codes into registers ----
        bf16x8 ch[4][4], cl[4][4];
        {
            const u16* cbase = frag + (size_t)(cg * 512 + wave * 64) * 256;
#pragma unroll
            for (int nt = 0; nt < 4; ++nt)
#pragma unroll
                for (int kb = 0; kb < 4; ++kb) {
                    const u16* p = cbase + (size_t)(nt * 16 + lr) * 256 + kb * 32 + lg * 8;
                    ch[nt][kb] = *reinterpret_cast<const bf16x8*>(p);
                    cl[nt][kb] = *reinterpret_cast<const bf16x8*>(p + 128);
                }
        }
        const int code0 = cg * 512 + wave * 64;

#pragma unroll 1
        for (int s = 0; s < 4; ++s) {       // z subchunks of 16 rows; barrier-free
            f32x4 acc[4];
#pragma unroll
            for (int nt = 0; nt < 4; ++nt) { acc[nt][0] = 0.f; acc[nt][1] = 0.f; acc[nt][2] = 0.f; acc[nt][3] = 0.f; }

            const int zrow = s * 16 + lr;   // B-operand col = z-row
#pragma unroll
            for (int kb = 0; kb < 4; ++kb) {
                int sb = (zrow * 256 + kb * 64 + lg * 16) ^ ((zrow & 7) << 4);
                bf16x8 zh = *reinterpret_cast<const bf16x8*>((char*)zsh + sb);
                bf16x8 zl = *reinterpret_cast<const bf16x8*>((char*)zsh + 16384 + sb);
#pragma unroll
                for (int nt = 0; nt < 4; ++nt) {
                    acc[nt] = __builtin_amdgcn_mfma_f32_16x16x32_bf16(ch[nt][kb], zh, acc[nt], 0, 0, 0);
                    acc[nt] = __builtin_amdgcn_mfma_f32_16x16x32_bf16(ch[nt][kb], zl, acc[nt], 0, 0, 0);
                    acc[nt] = __builtin_amdgcn_mfma_f32_16x16x32_bf16(cl[nt][kb], zh, acc[nt], 0, 0, 0);
                }
            }

            // epilogue: distances + plain stores (L2 line assembly) + per-lane top-2
            const float xn = xn_s[zrow];
            float* orow = out_dist + (size_t)(row_base + zrow) * K + code0 + lg * 4;
            float v1 = INFINITY, v2 = INFINITY;
            int i1 = K, i2 = K;
#pragma unroll
            for (int nt = 0; nt < 4; ++nt) {
                float4 cn4 = *reinterpret_cast<const float4*>(&cn_s[code0 + nt * 16 + lg * 4]);
                int cb0 = code0 + nt * 16 + lg * 4;
                float d0 = fmaf(-2.f, acc[nt][0], xn + cn4.x);
                float d1 = fmaf(-2.f, acc[nt][1], xn + cn4.y);
                float d2 = fmaf(-2.f, acc[nt][2], xn + cn4.z);
                float d3 = fmaf(-2.f, acc[nt][3], xn + cn4.w);
                if (d0 < v1) { v2 = v1; i2 = i1; v1 = d0; i1 = cb0; }
                else if (d0 < v2) { v2 = d0; i2 = cb0; }
                if (d1 < v1) { v2 = v1; i2 = i1; v1 = d1; i1 = cb0 + 1; }
                else if (d1 < v2) { v2 = d1; i2 = cb0 + 1; }
                if (d2 < v1) { v2 = v1; i2 = i1; v1 = d2; i1 = cb0 + 2; }
                else if (d2 < v2) { v2 = d2; i2 = cb0 + 2; }
                if (d3 < v1) { v2 = v1; i2 = i1; v1 = d3; i1 = cb0 + 3; }
                else if (d3 < v2) { v2 = d3; i2 = cb0 + 3; }
                f32x4 dv = {d0, d1, d2, d3};
                *reinterpret_cast<f32x4*>(orow + nt * 16) = dv;
            }

            // merge across lg groups (lanes sharing lr), flush to LDS slot
#pragma unroll
            for (int m = 16; m <= 32; m <<= 1) {
                float bv1 = __shfl_xor(v1, m), bv2 = __shfl_xor(v2, m);
                int bi1 = __shfl_xor(i1, m), bi2 = __shfl_xor(i2, m);
                t2merge(v1, i1, v2, i2, bv1, bi1, bv2, bi2);
            }
            if (lane < 16) {
                float4 p;
                p.x = v1; p.y = v2;
                p.z = __int_as_float(i1); p.w = __int_as_float(i2);
                scr[(cg * 8 + wave) * 64 + (s * 16 + lane)] = p;   // slot-major: conflict-free
            }
        }
    }
    __syncthreads();    // all top-2 slots written

    // ---- per-row reduce over 16 slots ----
    if (t < 64) {
        float bv = INFINITY, sv = INFINITY;
        int bi = K, si = K;
#pragma unroll
        for (int j = 0; j < 16; ++j) {
            float4 p = scr[j * 64 + t];
            t2merge(bv, bi, sv, si, p.x, __float_as_int(p.z), p.y, __float_as_int(p.w));
        }
        bi_s[t] = bi;
        si_s[t] = si;
    }
    __syncthreads();

    // ---- fp64 refinement (4 threads/row) + idx + hist + loss ----
    float lossv = 0.f;
    if (t < 256) {
        const int rr = t >> 2, t4 = t & 3;
        const int bi = bi_s[rr], si = si_s[rr];
        const float4* zr = reinterpret_cast<const float4*>(z + (size_t)(row_base + rr) * D);
        const float4* c1 = reinterpret_cast<const float4*>(codebook + (size_t)bi * D);
        const float4* c2 = reinterpret_cast<const float4*>(codebook + (size_t)si * D);
        double dd1 = 0.0, dd2 = 0.0;
#pragma unroll
        for (int j = 0; j < 8; ++j) {
            float4 xv = zr[t4 * 8 + j];
            float4 a = c1[t4 * 8 + j];
            float4 b = c2[t4 * 8 + j];
            double e;
            e = (double)xv.x - (double)a.x; dd1 += e * e;
            e = (double)xv.y - (double)a.y; dd1 += e * e;
            e = (double)xv.z - (double)a.z; dd1 += e * e;
            e = (double)xv.w - (double)a.w; dd1 += e * e;
            e = (double)xv.x - (double)b.x; dd2 += e * e;
            e = (double)xv.y - (double)b.y; dd2 += e * e;
            e = (double)xv.z - (double)b.z; dd2 += e * e;
            e = (double)xv.w - (double)b.w; dd2 += e * e;
        }
        dd1 += __shfl_xor(dd1, 1); dd1 += __shfl_xor(dd1, 2);
        dd2 += __shfl_xor(dd2, 1); dd2 += __shfl_xor(dd2, 2);
        if (t4 == 0) {
            int fi = bi; double dmin = dd1;
            if (dd2 < dd1 || (dd2 == dd1 && si < bi)) { fi = si; dmin = dd2; }
            best_s[rr] = fi;
            out_idx[row_base + rr] = (float)fi;
            atomicAdd(&hist[fi], 1);
            lossv = (float)dmin;
        }
    }
#pragma unroll
    for (int o = 32; o > 0; o >>= 1) lossv += __shfl_down(lossv, o);
    if (lane == 0) atomicAdd(loss_accum, lossv);
    __syncthreads();

    // ---- z_q gather (coalesced; codebook L2-resident) ----
    {
        const float4* cb4 = reinterpret_cast<const float4*>(codebook);
        float4* zq4 = reinterpret_cast<float4*>(out_zq + (size_t)row_base * D);
#pragma unroll
        for (int k = 0; k < 4; ++k) {
            int f = t + k * 512;
            int r = f >> 5, d4 = f & 31;
            zq4[f] = cb4[(size_t)best_s[r] * 32 + d4];
        }
    }
}

__global__ void vq_finalize(const int* __restrict__ hist, const float* __restrict__ loss_accum,
                            float* __restrict__ out_scalars, int M) {
    __shared__ float red[256];
    int t = threadIdx.x;
    float s = 0.f;
    float invM = 1.0f / (float)M;
#pragma unroll
    for (int k = 0; k < K / 256; ++k) {
        float p = (float)hist[t + k * 256] * invM;
        s += p * logf(p + 1e-10f);
    }
    red[t] = s;
    __syncthreads();
    for (int off = 128; off > 0; off >>= 1) {
        if (t < off) red[t] += red[t + off];
        __syncthreads();
    }
    if (t == 0) {
        float loss = loss_accum[0] / ((float)M * (float)D);
        out_scalars[0] = 0.25f * loss;    // commit_loss
        out_scalars[1] = loss;            // codebook_loss
        out_scalars[2] = expf(-red[0]);   // perplexity
    }
}

extern "C" void kernel_launch(void* const* d_in, const int* in_sizes, int n_in,
                              void* d_out, int out_size, void* d_ws, size_t ws_size,
                              hipStream_t stream) {
    const float* z = (const float*)d_in[0];
    const float* codebook = (const float*)d_in[1];
    int M = in_sizes[0] / D;   // 32768

    float* out = (float*)d_out;
    float* out_zq = out;                    // M*D
    float* out_idx = out + (size_t)M * D;   // M
    float* out_scalars = out_idx + M;       // 3
    float* out_dist = out_scalars + 3;      // M*K

    int* hist = (int*)d_ws;
    float* loss_accum = (float*)((char*)d_ws + 4096);
    float* cnorm = (float*)((char*)d_ws + 8192);
    u16* frag = (u16*)((char*)d_ws + 16384);

    prep2<<<(K * D / 4) / 256, 256, 0, stream>>>(codebook, frag, cnorm, hist, loss_accum);
    vq_all<<<M / 64, 512, 0, stream>>>(z, codebook, frag, cnorm, hist, loss_accum,
                                       out_zq, out_idx, out_dist);
    vq_finalize<<<1, 256, 0, stream>>>(hist, loss_accum, out_scalars, M);
}